// Round 1
// baseline (823.208 us; speedup 1.0000x reference)
//
#include <hip/hip_runtime.h>

// SAGEConv x2 forward:
//   deg = histogram(dst); dinv = 1/max(deg,1)
//   h = LR( segsum((x@Wl1)[src],dst)*dinv + x@Wr1 + b1 )
//   z = LR( segsum((h@Wl2)[src],dst)*dinv + h@Wr2 + b2 )
// Uses linearity of segment_sum to aggregate in the PROJECTED (narrow) dim.

constexpr int IN_DIM  = 128;
constexpr int HID     = 64;
constexpr int OUT_DIM = 32;
constexpr float SLOPE = 0.1f;

__global__ void deg_kernel(const int* __restrict__ dst, float* __restrict__ deg, int E) {
    int e = blockIdx.x * blockDim.x + threadIdx.x;
    if (e < E) atomicAdd(&deg[dst[e]], 1.0f);
}

// x[N,128] @ [Wl1 | Wr1] -> xl[N,64], xr[N,64](+b1). One thread per output col,
// 8 nodes per block staged in LDS, W rows streamed from L2 (shared across blocks).
__global__ __launch_bounds__(128) void gemm1_kernel(
    const float* __restrict__ x, const float* __restrict__ Wl,
    const float* __restrict__ Wr, const float* __restrict__ b1,
    float* __restrict__ xl, float* __restrict__ xr, int N) {
    __shared__ float xs[8][IN_DIM];
    const int c  = threadIdx.x;          // 0..127
    const int n0 = blockIdx.x * 8;
#pragma unroll
    for (int n = 0; n < 8; ++n) {
        int node = n0 + n;
        xs[n][c] = (node < N) ? x[(long)node * IN_DIM + c] : 0.f;
    }
    __syncthreads();
    const float* W = (c < HID) ? Wl : Wr;
    const int cc = c & (HID - 1);
    float acc[8] = {};
    for (int k = 0; k < IN_DIM; k += 4) {
        float w0 = W[(k + 0) * HID + cc];
        float w1 = W[(k + 1) * HID + cc];
        float w2 = W[(k + 2) * HID + cc];
        float w3 = W[(k + 3) * HID + cc];
#pragma unroll
        for (int n = 0; n < 8; ++n) {
            float4 xv = *reinterpret_cast<const float4*>(&xs[n][k]);
            acc[n] = fmaf(xv.x, w0, acc[n]);
            acc[n] = fmaf(xv.y, w1, acc[n]);
            acc[n] = fmaf(xv.z, w2, acc[n]);
            acc[n] = fmaf(xv.w, w3, acc[n]);
        }
    }
    const float bias = (c >= HID) ? b1[cc] : 0.f;
#pragma unroll
    for (int n = 0; n < 8; ++n) {
        int node = n0 + n;
        if (node < N) {
            if (c < HID) xl[(long)node * HID + cc] = acc[n];
            else         xr[(long)node * HID + cc] = acc[n] + bias;
        }
    }
}

// agg[dst[e]][f] += val[src[e]][f]  — one thread per (edge, feature).
// For D=64 a whole wave shares one edge (index loads hit one cache line).
template <int D>
__global__ void scatter_kernel(const int* __restrict__ src, const int* __restrict__ dst,
                               const float* __restrict__ val, float* __restrict__ agg, int E) {
    int t = blockIdx.x * blockDim.x + threadIdx.x;
    int e = t / D;
    int f = t % D;
    if (e < E) {
        atomicAdd(&agg[(long)dst[e] * D + f], val[(long)src[e] * D + f]);
    }
}

// h = LR(agg1*dinv + xr) computed into LDS (never materialized in HBM),
// then h @ [Wl2 | Wr2] -> hl[N,32], hr[N,32](+b2). Weights cached in LDS.
__global__ __launch_bounds__(256) void mid_kernel(
    const float* __restrict__ agg1, const float* __restrict__ xr,
    const float* __restrict__ deg,
    const float* __restrict__ Wl2, const float* __restrict__ Wr2,
    const float* __restrict__ b2,
    float* __restrict__ hl, float* __restrict__ hr, int N) {
    __shared__ float Wc[HID][HID];   // 16 KB: cols 0..31 = Wl2, 32..63 = Wr2
    __shared__ float hrow[4][HID];
    for (int i = threadIdx.x; i < HID * HID; i += 256) {
        int f = i >> 6, c = i & 63;
        Wc[f][c] = (c < OUT_DIM) ? Wl2[f * OUT_DIM + c]
                                 : Wr2[f * OUT_DIM + (c - OUT_DIM)];
    }
    const int lane = threadIdx.x & 63;
    const int nl   = threadIdx.x >> 6;   // wave id 0..3 -> node within group
    const int ngroups = (N + 3) >> 2;
    for (int g = blockIdx.x; g < ngroups; g += gridDim.x) {
        __syncthreads();                 // protects Wc (1st iter) + hrow reuse
        const int node = g * 4 + nl;
        float v = 0.f;
        if (node < N) {
            float dinv = 1.f / fmaxf(deg[node], 1.f);
            v = fmaf(agg1[(long)node * HID + lane], dinv, xr[(long)node * HID + lane]);
            v = (v > 0.f) ? v : SLOPE * v;
        }
        hrow[nl][lane] = v;
        __syncthreads();
        float acc = 0.f;
        const int c = lane;
        for (int k = 0; k < HID; k += 4) {
            float4 hv = *reinterpret_cast<const float4*>(&hrow[nl][k]);
            acc = fmaf(hv.x, Wc[k + 0][c], acc);
            acc = fmaf(hv.y, Wc[k + 1][c], acc);
            acc = fmaf(hv.z, Wc[k + 2][c], acc);
            acc = fmaf(hv.w, Wc[k + 3][c], acc);
        }
        if (node < N) {
            if (c < OUT_DIM) hl[(long)node * OUT_DIM + c] = acc;
            else             hr[(long)node * OUT_DIM + (c - OUT_DIM)] = acc + b2[c - OUT_DIM];
        }
    }
}

__global__ void final_kernel(const float* __restrict__ agg2, const float* __restrict__ hr,
                             const float* __restrict__ deg, float* __restrict__ z, int total) {
    int t = blockIdx.x * blockDim.x + threadIdx.x;
    if (t < total) {
        int n = t >> 5;  // OUT_DIM = 32
        float dinv = 1.f / fmaxf(deg[n], 1.f);
        float v = fmaf(agg2[t], dinv, hr[t]);
        z[t] = (v > 0.f) ? v : SLOPE * v;
    }
}

extern "C" void kernel_launch(void* const* d_in, const int* in_sizes, int n_in,
                              void* d_out, int out_size, void* d_ws, size_t ws_size,
                              hipStream_t stream) {
    const float* x   = (const float*)d_in[0];
    const int*   ei  = (const int*)d_in[1];
    const float* Wl1 = (const float*)d_in[2];
    const float* Wr1 = (const float*)d_in[3];
    const float* b1  = (const float*)d_in[4];
    const float* Wl2 = (const float*)d_in[5];
    const float* Wr2 = (const float*)d_in[6];
    const float* b2  = (const float*)d_in[7];

    const int N = in_sizes[0] / IN_DIM;
    const int E = in_sizes[1] / 2;
    const int* src = ei;
    const int* dst = ei + E;

    // Workspace layout (floats):
    // [ deg N | agg1 N*64 | agg2 N*32 | xl N*64 (later reused as hl|hr) | xr N*64 ]
    float* ws   = (float*)d_ws;
    float* deg  = ws;
    float* agg1 = deg + N;
    float* agg2 = agg1 + (size_t)N * HID;
    float* xl   = agg2 + (size_t)N * OUT_DIM;
    float* xr   = xl + (size_t)N * HID;
    float* hl   = xl;                          // alias: xl dead after scatter1
    float* hr   = xl + (size_t)N * OUT_DIM;

    // zero deg + agg1 + agg2 (contiguous)
    hipMemsetAsync(deg, 0, sizeof(float) * (size_t)N * (1 + HID + OUT_DIM), stream);

    deg_kernel<<<(E + 255) / 256, 256, 0, stream>>>(dst, deg, E);
    gemm1_kernel<<<(N + 7) / 8, 128, 0, stream>>>(x, Wl1, Wr1, b1, xl, xr, N);
    scatter_kernel<HID><<<(int)(((long)E * HID + 255) / 256), 256, 0, stream>>>(src, dst, xl, agg1, E);
    mid_kernel<<<2048, 256, 0, stream>>>(agg1, xr, deg, Wl2, Wr2, b2, hl, hr, N);
    scatter_kernel<OUT_DIM><<<(int)(((long)E * OUT_DIM + 255) / 256), 256, 0, stream>>>(src, dst, hl, agg2, E);
    final_kernel<<<(N * OUT_DIM + 255) / 256, 256, 0, stream>>>(agg2, hr, deg, (float*)d_out, N * OUT_DIM);
}

// Round 2
// 645.843 us; speedup vs baseline: 1.2746x; 1.2746x over previous
//
#include <hip/hip_runtime.h>

// SAGEConv x2 forward, CSR-based (no float atomics):
//   deg = histogram(dst); rowptr = exscan(deg); srcs = edges binned by dst
//   xl = x@Wl1 ; xr = x@Wr1+b1                       (gemm1)
//   h  = LR(gather-sum(xl)*dinv + xr); [hl|hr] = h@[Wl2|Wr2](+b2)   (agg_mid, fused)
//   z  = LR(gather-sum(hl)*dinv + hr)               (agg2_final, fused)
// Aggregation happens in the PROJECTED (narrow) dims: 64 then 32.

constexpr int IN_DIM  = 128;
constexpr int HID     = 64;
constexpr int OUT_DIM = 32;
constexpr float SLOPE = 0.1f;

__global__ void deg_kernel(const int* __restrict__ dst, int* __restrict__ deg, int E) {
    int e = blockIdx.x * blockDim.x + threadIdx.x;
    if (e < E) atomicAdd(&deg[dst[e]], 1);
}

// ---- 2-level exclusive scan over deg[N] -> rowptr[N] ----
__global__ __launch_bounds__(256) void scan_a(const int* __restrict__ deg,
                                              int* __restrict__ rp_part,
                                              int* __restrict__ bsum, int N) {
    __shared__ int s[256];
    int tid = threadIdx.x, i = blockIdx.x * 256 + tid;
    int v = (i < N) ? deg[i] : 0;
    s[tid] = v; __syncthreads();
    for (int off = 1; off < 256; off <<= 1) {
        int t = (tid >= off) ? s[tid - off] : 0;
        __syncthreads();
        s[tid] += t;
        __syncthreads();
    }
    if (i < N) rp_part[i] = s[tid] - v;          // exclusive within block
    if (tid == 255) bsum[blockIdx.x] = s[255];   // block total
}

__global__ __launch_bounds__(512) void scan_b(const int* __restrict__ bsum,
                                              int* __restrict__ boff, int nb) {
    __shared__ int s[512];
    int tid = threadIdx.x;
    int v = (tid < nb) ? bsum[tid] : 0;
    s[tid] = v; __syncthreads();
    for (int off = 1; off < 512; off <<= 1) {
        int t = (tid >= off) ? s[tid - off] : 0;
        __syncthreads();
        s[tid] += t;
        __syncthreads();
    }
    boff[tid] = s[tid] - v;                      // exclusive block offsets
}

__global__ void scan_c(const int* __restrict__ rp_part, const int* __restrict__ boff,
                       int* __restrict__ rowptr, int* __restrict__ cursor, int N) {
    int i = blockIdx.x * blockDim.x + threadIdx.x;
    if (i < N) { int v = rp_part[i] + boff[i >> 8]; rowptr[i] = v; cursor[i] = v; }
}

__global__ void bin_kernel(const int* __restrict__ src, const int* __restrict__ dst,
                           int* __restrict__ cursor, int* __restrict__ srcs, int E) {
    int e = blockIdx.x * blockDim.x + threadIdx.x;
    if (e < E) { int p = atomicAdd(&cursor[dst[e]], 1); srcs[p] = src[e]; }
}

// ---- x[N,128] @ [Wl1 | Wr1] -> xl[N,64], xr[N,64](+b1) ----
__global__ __launch_bounds__(128) void gemm1_kernel(
    const float* __restrict__ x, const float* __restrict__ Wl,
    const float* __restrict__ Wr, const float* __restrict__ b1,
    float* __restrict__ xl, float* __restrict__ xr, int N) {
    __shared__ float xs[8][IN_DIM];
    const int c  = threadIdx.x;
    const int n0 = blockIdx.x * 8;
#pragma unroll
    for (int n = 0; n < 8; ++n) {
        int node = n0 + n;
        xs[n][c] = (node < N) ? x[(long)node * IN_DIM + c] : 0.f;
    }
    __syncthreads();
    const float* W = (c < HID) ? Wl : Wr;
    const int cc = c & (HID - 1);
    float acc[8] = {};
    for (int k = 0; k < IN_DIM; k += 4) {
        float w0 = W[(k + 0) * HID + cc];
        float w1 = W[(k + 1) * HID + cc];
        float w2 = W[(k + 2) * HID + cc];
        float w3 = W[(k + 3) * HID + cc];
#pragma unroll
        for (int n = 0; n < 8; ++n) {
            float4 xv = *reinterpret_cast<const float4*>(&xs[n][k]);
            acc[n] = fmaf(xv.x, w0, acc[n]);
            acc[n] = fmaf(xv.y, w1, acc[n]);
            acc[n] = fmaf(xv.z, w2, acc[n]);
            acc[n] = fmaf(xv.w, w3, acc[n]);
        }
    }
    const float bias = (c >= HID) ? b1[cc] : 0.f;
#pragma unroll
    for (int n = 0; n < 8; ++n) {
        int node = n0 + n;
        if (node < N) {
            if (c < HID) xl[(long)node * HID + cc] = acc[n];
            else         xr[(long)node * HID + cc] = acc[n] + bias;
        }
    }
}

// ---- fused: agg1 gather-sum + leaky_relu + h@[Wl2|Wr2] -> hl,hr ----
// One wave per node; lane = feature (64). h never touches HBM.
__global__ __launch_bounds__(256) void agg_mid_kernel(
    const int* __restrict__ rowptr, const int* __restrict__ deg,
    const int* __restrict__ srcs,
    const float* __restrict__ xl, const float* __restrict__ xr,
    const float* __restrict__ Wl2, const float* __restrict__ Wr2,
    const float* __restrict__ b2,
    float* __restrict__ hl, float* __restrict__ hr, int N) {
    __shared__ float Wc[HID][HID];   // 16 KB: cols 0..31 = Wl2, 32..63 = Wr2
    for (int i = threadIdx.x; i < HID * HID; i += 256) {
        int k = i >> 6, c = i & 63;
        Wc[k][c] = (c < OUT_DIM) ? Wl2[k * OUT_DIM + c]
                                 : Wr2[k * OUT_DIM + (c - OUT_DIM)];
    }
    __syncthreads();   // only barrier; per-wave work below is independent
    const int lane   = threadIdx.x & 63;
    const int gw     = blockIdx.x * 4 + (threadIdx.x >> 6);
    const int stride = gridDim.x * 4;
    for (int n = gw; n < N; n += stride) {
        const int rp = rowptr[n], d = deg[n];
        float a0 = 0.f, a1 = 0.f, a2 = 0.f, a3 = 0.f;
        int j = 0;
        while (j < d) {
            int cnt = min(64, d - j);
            int sid = (lane < cnt) ? srcs[rp + j + lane] : 0;  // coalesced id batch
            int i = 0;
            for (; i + 4 <= cnt; i += 4) {
                int s0 = __shfl(sid, i), s1 = __shfl(sid, i + 1);
                int s2 = __shfl(sid, i + 2), s3 = __shfl(sid, i + 3);
                a0 += xl[(long)s0 * HID + lane];
                a1 += xl[(long)s1 * HID + lane];
                a2 += xl[(long)s2 * HID + lane];
                a3 += xl[(long)s3 * HID + lane];
            }
            for (; i < cnt; ++i) {
                int s = __shfl(sid, i);
                a0 += xl[(long)s * HID + lane];
            }
            j += cnt;
        }
        float acc  = (a0 + a1) + (a2 + a3);
        float dinv = 1.f / fmaxf((float)d, 1.f);
        float v    = fmaf(acc, dinv, xr[(long)n * HID + lane]);
        v = (v > 0.f) ? v : SLOPE * v;          // h value, one per lane
        // project: out[c] = sum_k h[k] * Wc[k][c]  (readlane broadcast)
        float o = 0.f;
#pragma unroll
        for (int k = 0; k < HID; ++k) {
            float hk = __shfl(v, k);             // uniform k -> v_readlane
            o = fmaf(hk, Wc[k][lane], o);
        }
        if (lane < OUT_DIM) hl[(long)n * OUT_DIM + lane] = o;
        else hr[(long)n * OUT_DIM + (lane - OUT_DIM)] = o + b2[lane - OUT_DIM];
    }
}

// ---- fused: agg2 gather-sum + leaky_relu -> z (d_out) ----
// One wave per node; lanes 32..63 mirror 0..31; only lanes<32 write.
__global__ __launch_bounds__(256) void agg2_final_kernel(
    const int* __restrict__ rowptr, const int* __restrict__ deg,
    const int* __restrict__ srcs,
    const float* __restrict__ hl, const float* __restrict__ hr,
    float* __restrict__ z, int N) {
    const int lane = threadIdx.x & 63;
    const int f    = lane & 31;
    const int n    = blockIdx.x * 4 + (threadIdx.x >> 6);
    if (n >= N) return;
    const int rp = rowptr[n], d = deg[n];
    float a0 = 0.f, a1 = 0.f;
    int j = 0;
    while (j < d) {
        int cnt = min(32, d - j);
        int sid = (f < cnt) ? srcs[rp + j + f] : 0;
        int i = 0;
        for (; i + 2 <= cnt; i += 2) {
            int s0 = __shfl(sid, i), s1 = __shfl(sid, i + 1);
            a0 += hl[(long)s0 * OUT_DIM + f];
            a1 += hl[(long)s1 * OUT_DIM + f];
        }
        for (; i < cnt; ++i) {
            int s = __shfl(sid, i);
            a0 += hl[(long)s * OUT_DIM + f];
        }
        j += cnt;
    }
    float acc  = a0 + a1;
    float dinv = 1.f / fmaxf((float)d, 1.f);
    float v    = fmaf(acc, dinv, hr[(long)n * OUT_DIM + f]);
    v = (v > 0.f) ? v : SLOPE * v;
    if (lane < OUT_DIM) z[(long)n * OUT_DIM + f] = v;
}

extern "C" void kernel_launch(void* const* d_in, const int* in_sizes, int n_in,
                              void* d_out, int out_size, void* d_ws, size_t ws_size,
                              hipStream_t stream) {
    const float* x   = (const float*)d_in[0];
    const int*   ei  = (const int*)d_in[1];
    const float* Wl1 = (const float*)d_in[2];
    const float* Wr1 = (const float*)d_in[3];
    const float* b1  = (const float*)d_in[4];
    const float* Wl2 = (const float*)d_in[5];
    const float* Wr2 = (const float*)d_in[6];
    const float* b2  = (const float*)d_in[7];

    const int N = in_sizes[0] / IN_DIM;
    const int E = in_sizes[1] / 2;
    const int* src = ei;
    const int* dst = ei + E;
    const int nb = (N + 255) / 256;   // scan blocks (<=512)

    // Workspace layout
    char* p = (char*)d_ws;
    int* deg     = (int*)p;            p += sizeof(int) * N;
    int* rp_part = (int*)p;            p += sizeof(int) * N;
    int* rowptr  = (int*)p;            p += sizeof(int) * N;
    int* cursor  = (int*)p;            p += sizeof(int) * N;
    int* bsum    = (int*)p;            p += sizeof(int) * 512;
    int* boff    = (int*)p;            p += sizeof(int) * 512;
    int* srcs    = (int*)p;            p += sizeof(int) * E;
    float* xl    = (float*)p;          p += sizeof(float) * (size_t)N * HID;
    float* xr    = (float*)p;          p += sizeof(float) * (size_t)N * HID;
    float* hl    = (float*)p;          p += sizeof(float) * (size_t)N * OUT_DIM;
    float* hr    = (float*)p;          p += sizeof(float) * (size_t)N * OUT_DIM;

    hipMemsetAsync(deg, 0, sizeof(int) * N, stream);

    deg_kernel<<<(E + 255) / 256, 256, 0, stream>>>(dst, deg, E);
    scan_a<<<nb, 256, 0, stream>>>(deg, rp_part, bsum, N);
    scan_b<<<1, 512, 0, stream>>>(bsum, boff, nb);
    scan_c<<<(N + 255) / 256, 256, 0, stream>>>(rp_part, boff, rowptr, cursor, N);
    bin_kernel<<<(E + 255) / 256, 256, 0, stream>>>(src, dst, cursor, srcs, E);
    gemm1_kernel<<<(N + 7) / 8, 128, 0, stream>>>(x, Wl1, Wr1, b1, xl, xr, N);
    agg_mid_kernel<<<2048, 256, 0, stream>>>(rowptr, deg, srcs, xl, xr,
                                             Wl2, Wr2, b2, hl, hr, N);
    agg2_final_kernel<<<(N + 3) / 4, 256, 0, stream>>>(rowptr, deg, srcs, hl, hr,
                                                       (float*)d_out, N);
}

// Round 3
// 529.211 us; speedup vs baseline: 1.5555x; 1.2204x over previous
//
#include <hip/hip_runtime.h>

// SAGEConv x2 forward, CSR-based, bf16 gather payloads:
//   deg = histogram(dst); rowptr = exscan(deg); srcs = edges binned by dst
//   xl = bf16(x@Wl1) ; xr = x@Wr1+b1                 (gemm1)
//   h  = LR(gather-sum(xl)*dinv + xr); [hl|hr] = h@[Wl2|Wr2](+b2)  (agg_mid)
//   z  = LR(gather-sum(hl)*dinv + hr)                (agg2_final)
// Gathers use packed-bf16 pairs: one load instr covers 2 (layer1) / 4 (layer2)
// rows; 4 (resp 2) chains -> 8 rows in flight per wave.

constexpr int IN_DIM  = 128;
constexpr int HID     = 64;
constexpr int OUT_DIM = 32;
constexpr float SLOPE = 0.1f;

typedef unsigned int uint32;
typedef unsigned short ushort16;

__device__ inline float blo(uint32 u) { return __uint_as_float(u << 16); }
__device__ inline float bhi(uint32 u) { return __uint_as_float(u & 0xffff0000u); }
__device__ inline ushort16 f2b(float f) {
    uint32 u = __float_as_uint(f);
    u += 0x7fffu + ((u >> 16) & 1u);   // round-to-nearest-even
    return (ushort16)(u >> 16);
}

__global__ void deg_kernel(const int* __restrict__ dst, int* __restrict__ deg, int E) {
    int e = blockIdx.x * blockDim.x + threadIdx.x;
    if (e < E) atomicAdd(&deg[dst[e]], 1);
}

// ---- 2-level exclusive scan over deg[N] -> rowptr[N+1] ----
__global__ __launch_bounds__(256) void scan_a(const int* __restrict__ deg,
                                              int* __restrict__ rp_part,
                                              int* __restrict__ bsum, int N) {
    __shared__ int s[256];
    int tid = threadIdx.x, i = blockIdx.x * 256 + tid;
    int v = (i < N) ? deg[i] : 0;
    s[tid] = v; __syncthreads();
    for (int off = 1; off < 256; off <<= 1) {
        int t = (tid >= off) ? s[tid - off] : 0;
        __syncthreads();
        s[tid] += t;
        __syncthreads();
    }
    if (i < N) rp_part[i] = s[tid] - v;
    if (tid == 255) bsum[blockIdx.x] = s[255];
}

__global__ __launch_bounds__(512) void scan_b(const int* __restrict__ bsum,
                                              int* __restrict__ boff, int nb) {
    __shared__ int s[512];
    int tid = threadIdx.x;
    int v = (tid < nb) ? bsum[tid] : 0;
    s[tid] = v; __syncthreads();
    for (int off = 1; off < 512; off <<= 1) {
        int t = (tid >= off) ? s[tid - off] : 0;
        __syncthreads();
        s[tid] += t;
        __syncthreads();
    }
    boff[tid] = s[tid] - v;
}

__global__ void scan_c(const int* __restrict__ rp_part, const int* __restrict__ boff,
                       const int* __restrict__ deg,
                       int* __restrict__ rowptr, int* __restrict__ cursor, int N) {
    int i = blockIdx.x * blockDim.x + threadIdx.x;
    if (i < N) {
        int v = rp_part[i] + boff[i >> 8];
        rowptr[i] = v; cursor[i] = v;
        if (i == N - 1) rowptr[N] = v + deg[i];
    }
}

__global__ void bin_kernel(const int* __restrict__ src, const int* __restrict__ dst,
                           int* __restrict__ cursor, int* __restrict__ srcs, int E) {
    int e = blockIdx.x * blockDim.x + threadIdx.x;
    if (e < E) { int p = atomicAdd(&cursor[dst[e]], 1); srcs[p] = src[e]; }
}

// ---- x[N,128] @ [Wl1 | Wr1] -> xl bf16[N,64], xr fp32[N,64](+b1) ----
__global__ __launch_bounds__(128) void gemm1_kernel(
    const float* __restrict__ x, const float* __restrict__ Wl,
    const float* __restrict__ Wr, const float* __restrict__ b1,
    ushort16* __restrict__ xl, float* __restrict__ xr, int N) {
    __shared__ float xs[8][IN_DIM];
    const int c  = threadIdx.x;
    const int n0 = blockIdx.x * 8;
#pragma unroll
    for (int n = 0; n < 8; ++n) {
        int node = n0 + n;
        xs[n][c] = (node < N) ? x[(long)node * IN_DIM + c] : 0.f;
    }
    __syncthreads();
    const float* W = (c < HID) ? Wl : Wr;
    const int cc = c & (HID - 1);
    float acc[8] = {};
    for (int k = 0; k < IN_DIM; k += 4) {
        float w0 = W[(k + 0) * HID + cc];
        float w1 = W[(k + 1) * HID + cc];
        float w2 = W[(k + 2) * HID + cc];
        float w3 = W[(k + 3) * HID + cc];
#pragma unroll
        for (int n = 0; n < 8; ++n) {
            float4 xv = *reinterpret_cast<const float4*>(&xs[n][k]);
            acc[n] = fmaf(xv.x, w0, acc[n]);
            acc[n] = fmaf(xv.y, w1, acc[n]);
            acc[n] = fmaf(xv.z, w2, acc[n]);
            acc[n] = fmaf(xv.w, w3, acc[n]);
        }
    }
    const float bias = (c >= HID) ? b1[cc] : 0.f;
#pragma unroll
    for (int n = 0; n < 8; ++n) {
        int node = n0 + n;
        if (node < N) {
            if (c < HID) xl[(long)node * HID + cc] = f2b(acc[n]);
            else         xr[(long)node * HID + cc] = acc[n] + bias;
        }
    }
}

// ---- fused: agg1 gather-sum(bf16) + LR + h@[Wl2|Wr2] -> hl(bf16), hr(fp32) ----
// One wave per node iter. Lane layout: half=lane>>5 picks edge parity,
// li=lane&31 picks feature-pair (2li, 2li+1). One load instr = 2 rows.
__global__ __launch_bounds__(256) void agg_mid_kernel(
    const int* __restrict__ rowptr, const int* __restrict__ srcs,
    const uint32* __restrict__ xlu,   // row n at xlu + n*32
    const float* __restrict__ xr,
    const float* __restrict__ Wl2, const float* __restrict__ Wr2,
    const float* __restrict__ b2,
    ushort16* __restrict__ hl, float* __restrict__ hr, int N) {
    __shared__ float Wc[HID][HID];   // 16 KB: cols 0..31 = Wl2, 32..63 = Wr2
    for (int i = threadIdx.x; i < HID * HID; i += 256) {
        int k = i >> 6, c = i & 63;
        Wc[k][c] = (c < OUT_DIM) ? Wl2[k * OUT_DIM + c]
                                 : Wr2[k * OUT_DIM + (c - OUT_DIM)];
    }
    __syncthreads();
    const int lane = threadIdx.x & 63;
    const int half = lane >> 5;        // 0/1: which edge of a pair
    const int li   = lane & 31;        // feature pair index
    const int gw     = blockIdx.x * 4 + (threadIdx.x >> 6);
    const int stride = gridDim.x * 4;
    for (int n = gw; n < N; n += stride) {
        const int rp = rowptr[n];
        const int d  = rowptr[n + 1] - rp;
        float2 xr2 = *reinterpret_cast<const float2*>(&xr[(long)n * HID + 2 * li]);
        float2 a0 = {0.f, 0.f}, a1 = {0.f, 0.f}, a2 = {0.f, 0.f}, a3 = {0.f, 0.f};
        int j = 0;
        while (j < d) {
            int cnt = min(64, d - j);
            int sid = (lane < cnt) ? srcs[rp + j + lane] : 0;
            int i = 0;
            for (; i + 8 <= cnt; i += 8) {
                int s0 = __shfl(sid, i + 0 + half);
                int s1 = __shfl(sid, i + 2 + half);
                int s2 = __shfl(sid, i + 4 + half);
                int s3 = __shfl(sid, i + 6 + half);
                uint32 u0 = xlu[(long)s0 * 32 + li];
                uint32 u1 = xlu[(long)s1 * 32 + li];
                uint32 u2 = xlu[(long)s2 * 32 + li];
                uint32 u3 = xlu[(long)s3 * 32 + li];
                a0.x += blo(u0); a0.y += bhi(u0);
                a1.x += blo(u1); a1.y += bhi(u1);
                a2.x += blo(u2); a2.y += bhi(u2);
                a3.x += blo(u3); a3.y += bhi(u3);
            }
            for (; i + 2 <= cnt; i += 2) {
                int s = __shfl(sid, i + half);
                uint32 u = xlu[(long)s * 32 + li];
                a0.x += blo(u); a0.y += bhi(u);
            }
            if (i < cnt) {                       // odd leftover row
                int s = __shfl(sid, i);
                if (half == 0) {
                    uint32 u = xlu[(long)s * 32 + li];
                    a0.x += blo(u); a0.y += bhi(u);
                }
            }
            j += cnt;
        }
        float2 acc;
        acc.x = (a0.x + a1.x) + (a2.x + a3.x);
        acc.y = (a0.y + a1.y) + (a2.y + a3.y);
        acc.x += __shfl_xor(acc.x, 32);          // combine edge-parity halves
        acc.y += __shfl_xor(acc.y, 32);
        float dinv = 1.f / fmaxf((float)d, 1.f);
        float2 v;
        v.x = fmaf(acc.x, dinv, xr2.x);
        v.y = fmaf(acc.y, dinv, xr2.y);
        v.x = (v.x > 0.f) ? v.x : SLOPE * v.x;   // h[2li], h[2li+1]
        v.y = (v.y > 0.f) ? v.y : SLOPE * v.y;
        // project: o[lane] = sum_k h[k] * Wc[k][lane]
        float o = 0.f;
#pragma unroll
        for (int m = 0; m < 32; ++m) {
            float hx = __shfl(v.x, m);
            float hy = __shfl(v.y, m);
            o = fmaf(hx, Wc[2 * m][lane], o);
            o = fmaf(hy, Wc[2 * m + 1][lane], o);
        }
        if (lane < OUT_DIM) hl[(long)n * OUT_DIM + lane] = f2b(o);
        else hr[(long)n * OUT_DIM + (lane - OUT_DIM)] = o + b2[lane - OUT_DIM];
    }
}

// ---- fused: agg2 gather-sum(bf16) + LR -> z. One wave per node. ----
// grp=lane>>4 picks row-of-4, li=lane&15 picks feature pair. 1 load = 4 rows.
__global__ __launch_bounds__(256) void agg2_final_kernel(
    const int* __restrict__ rowptr, const int* __restrict__ srcs,
    const uint32* __restrict__ hlu,   // row n at hlu + n*16
    const float* __restrict__ hr,
    float* __restrict__ z, int N) {
    const int lane = threadIdx.x & 63;
    const int grp  = lane >> 4;
    const int li   = lane & 15;
    const int n    = blockIdx.x * 4 + (threadIdx.x >> 6);
    if (n >= N) return;
    const int rp = rowptr[n];
    const int d  = rowptr[n + 1] - rp;
    float2 hr2 = *reinterpret_cast<const float2*>(&hr[(long)n * OUT_DIM + 2 * li]);
    float2 a0 = {0.f, 0.f}, a1 = {0.f, 0.f};
    int j = 0;
    while (j < d) {
        int cnt = min(64, d - j);
        int sid = (lane < cnt) ? srcs[rp + j + lane] : 0;
        int i = 0;
        for (; i + 8 <= cnt; i += 8) {
            int s0 = __shfl(sid, i + grp);
            int s1 = __shfl(sid, i + 4 + grp);
            uint32 u0 = hlu[(long)s0 * 16 + li];
            uint32 u1 = hlu[(long)s1 * 16 + li];
            a0.x += blo(u0); a0.y += bhi(u0);
            a1.x += blo(u1); a1.y += bhi(u1);
        }
        for (; i + 4 <= cnt; i += 4) {
            int s = __shfl(sid, i + grp);
            uint32 u = hlu[(long)s * 16 + li];
            a0.x += blo(u); a0.y += bhi(u);
        }
        int rem = cnt - i;
        if (rem > 0) {
            int s = __shfl(sid, i + (grp & 3));
            if (grp < rem) {
                uint32 u = hlu[(long)s * 16 + li];
                a0.x += blo(u); a0.y += bhi(u);
            }
        }
        j += cnt;
    }
    float2 acc;
    acc.x = a0.x + a1.x;
    acc.y = a0.y + a1.y;
    acc.x += __shfl_xor(acc.x, 16); acc.x += __shfl_xor(acc.x, 32);
    acc.y += __shfl_xor(acc.y, 16); acc.y += __shfl_xor(acc.y, 32);
    float dinv = 1.f / fmaxf((float)d, 1.f);
    float2 v;
    v.x = fmaf(acc.x, dinv, hr2.x);
    v.y = fmaf(acc.y, dinv, hr2.y);
    v.x = (v.x > 0.f) ? v.x : SLOPE * v.x;
    v.y = (v.y > 0.f) ? v.y : SLOPE * v.y;
    if (grp == 0) *reinterpret_cast<float2*>(&z[(long)n * OUT_DIM + 2 * li]) = v;
}

extern "C" void kernel_launch(void* const* d_in, const int* in_sizes, int n_in,
                              void* d_out, int out_size, void* d_ws, size_t ws_size,
                              hipStream_t stream) {
    const float* x   = (const float*)d_in[0];
    const int*   ei  = (const int*)d_in[1];
    const float* Wl1 = (const float*)d_in[2];
    const float* Wr1 = (const float*)d_in[3];
    const float* b1  = (const float*)d_in[4];
    const float* Wl2 = (const float*)d_in[5];
    const float* Wr2 = (const float*)d_in[6];
    const float* b2  = (const float*)d_in[7];

    const int N = in_sizes[0] / IN_DIM;
    const int E = in_sizes[1] / 2;
    const int* src = ei;
    const int* dst = ei + E;
    const int nb = (N + 255) / 256;

    char* p = (char*)d_ws;
    int* deg     = (int*)p;            p += sizeof(int) * N;
    int* rp_part = (int*)p;            p += sizeof(int) * N;
    int* rowptr  = (int*)p;            p += sizeof(int) * (N + 2);  // +2 keeps 8B align
    int* cursor  = (int*)p;            p += sizeof(int) * N;
    int* bsum    = (int*)p;            p += sizeof(int) * 512;
    int* boff    = (int*)p;            p += sizeof(int) * 512;
    int* srcs    = (int*)p;            p += sizeof(int) * E;
    ushort16* xl = (ushort16*)p;       p += sizeof(ushort16) * (size_t)N * HID;
    float* xr    = (float*)p;          p += sizeof(float) * (size_t)N * HID;
    ushort16* hl = (ushort16*)p;       p += sizeof(ushort16) * (size_t)N * OUT_DIM;
    float* hr    = (float*)p;          p += sizeof(float) * (size_t)N * OUT_DIM;

    hipMemsetAsync(deg, 0, sizeof(int) * N, stream);

    deg_kernel<<<(E + 255) / 256, 256, 0, stream>>>(dst, deg, E);
    scan_a<<<nb, 256, 0, stream>>>(deg, rp_part, bsum, N);
    scan_b<<<1, 512, 0, stream>>>(bsum, boff, nb);
    scan_c<<<(N + 255) / 256, 256, 0, stream>>>(rp_part, boff, deg, rowptr, cursor, N);
    bin_kernel<<<(E + 255) / 256, 256, 0, stream>>>(src, dst, cursor, srcs, E);
    gemm1_kernel<<<(N + 7) / 8, 128, 0, stream>>>(x, Wl1, Wr1, b1, xl, xr, N);
    agg_mid_kernel<<<(N + 15) / 16, 256, 0, stream>>>(rowptr, srcs, (const uint32*)xl, xr,
                                                      Wl2, Wr2, b2, hl, hr, N);
    agg2_final_kernel<<<(N + 3) / 4, 256, 0, stream>>>(rowptr, srcs, (const uint32*)hl, hr,
                                                       (float*)d_out, N);
}

// Round 4
// 464.288 us; speedup vs baseline: 1.7731x; 1.1398x over previous
//
#include <hip/hip_runtime.h>

// SAGEConv x2 forward, CSR-based, bf16 gather payloads.
// Aggregation kernels use SUB-WAVE GROUPS: one node per 8-lane (layer1) /
// 4-lane (layer2) group, uint4 (16B) gather loads, 8 gathers in flight per
// group => up to 64 outstanding loads per wave (latency hiding).
//   xl = bf16(x@Wl1) ; xr = x@Wr1+b1                  (gemm1)
//   h  = LR(gsum(xl)*dinv + xr); [hl|hr] = h@[Wl2|Wr2](+b2)  (agg_mid)
//   z  = LR(gsum(hl)*dinv + hr)                       (agg2_final)

constexpr int IN_DIM  = 128;
constexpr int HID     = 64;
constexpr int OUT_DIM = 32;
constexpr float SLOPE = 0.1f;

typedef unsigned int uint32;
typedef unsigned short ushort16;

__device__ inline float blo(uint32 u) { return __uint_as_float(u << 16); }
__device__ inline float bhi(uint32 u) { return __uint_as_float(u & 0xffff0000u); }
__device__ inline ushort16 f2b(float f) {
    uint32 u = __float_as_uint(f);
    u += 0x7fffu + ((u >> 16) & 1u);   // round-to-nearest-even
    return (ushort16)(u >> 16);
}
__device__ inline uint32 pack2(float lo, float hi) {
    return (uint32)f2b(lo) | ((uint32)f2b(hi) << 16);
}

__global__ void deg_kernel(const int* __restrict__ dst, int* __restrict__ deg, int E) {
    int e = blockIdx.x * blockDim.x + threadIdx.x;
    if (e < E) atomicAdd(&deg[dst[e]], 1);
}

// ---- 2-level exclusive scan over deg[N] -> rowptr[N+1] ----
__global__ __launch_bounds__(256) void scan_a(const int* __restrict__ deg,
                                              int* __restrict__ rp_part,
                                              int* __restrict__ bsum, int N) {
    __shared__ int s[256];
    int tid = threadIdx.x, i = blockIdx.x * 256 + tid;
    int v = (i < N) ? deg[i] : 0;
    s[tid] = v; __syncthreads();
    for (int off = 1; off < 256; off <<= 1) {
        int t = (tid >= off) ? s[tid - off] : 0;
        __syncthreads();
        s[tid] += t;
        __syncthreads();
    }
    if (i < N) rp_part[i] = s[tid] - v;
    if (tid == 255) bsum[blockIdx.x] = s[255];
}

__global__ __launch_bounds__(512) void scan_b(const int* __restrict__ bsum,
                                              int* __restrict__ boff, int nb) {
    __shared__ int s[512];
    int tid = threadIdx.x;
    int v = (tid < nb) ? bsum[tid] : 0;
    s[tid] = v; __syncthreads();
    for (int off = 1; off < 512; off <<= 1) {
        int t = (tid >= off) ? s[tid - off] : 0;
        __syncthreads();
        s[tid] += t;
        __syncthreads();
    }
    boff[tid] = s[tid] - v;
}

__global__ void scan_c(const int* __restrict__ rp_part, const int* __restrict__ boff,
                       const int* __restrict__ deg,
                       int* __restrict__ rowptr, int* __restrict__ cursor, int N) {
    int i = blockIdx.x * blockDim.x + threadIdx.x;
    if (i < N) {
        int v = rp_part[i] + boff[i >> 8];
        rowptr[i] = v; cursor[i] = v;
        if (i == N - 1) rowptr[N] = v + deg[i];
    }
}

__global__ void bin_kernel(const int* __restrict__ src, const int* __restrict__ dst,
                           int* __restrict__ cursor, int* __restrict__ srcs, int E) {
    int e = blockIdx.x * blockDim.x + threadIdx.x;
    if (e < E) { int p = atomicAdd(&cursor[dst[e]], 1); srcs[p] = src[e]; }
}

// ---- x[N,128] @ [Wl1 | Wr1] -> xl bf16[N,64], xr fp32[N,64](+b1) ----
__global__ __launch_bounds__(128) void gemm1_kernel(
    const float* __restrict__ x, const float* __restrict__ Wl,
    const float* __restrict__ Wr, const float* __restrict__ b1,
    ushort16* __restrict__ xl, float* __restrict__ xr, int N) {
    __shared__ float xs[8][IN_DIM];
    const int c  = threadIdx.x;
    const int n0 = blockIdx.x * 8;
#pragma unroll
    for (int n = 0; n < 8; ++n) {
        int node = n0 + n;
        xs[n][c] = (node < N) ? x[(long)node * IN_DIM + c] : 0.f;
    }
    __syncthreads();
    const float* W = (c < HID) ? Wl : Wr;
    const int cc = c & (HID - 1);
    float acc[8] = {};
    for (int k = 0; k < IN_DIM; k += 4) {
        float w0 = W[(k + 0) * HID + cc];
        float w1 = W[(k + 1) * HID + cc];
        float w2 = W[(k + 2) * HID + cc];
        float w3 = W[(k + 3) * HID + cc];
#pragma unroll
        for (int n = 0; n < 8; ++n) {
            float4 xv = *reinterpret_cast<const float4*>(&xs[n][k]);
            acc[n] = fmaf(xv.x, w0, acc[n]);
            acc[n] = fmaf(xv.y, w1, acc[n]);
            acc[n] = fmaf(xv.z, w2, acc[n]);
            acc[n] = fmaf(xv.w, w3, acc[n]);
        }
    }
    const float bias = (c >= HID) ? b1[cc] : 0.f;
#pragma unroll
    for (int n = 0; n < 8; ++n) {
        int node = n0 + n;
        if (node < N) {
            if (c < HID) xl[(long)node * HID + cc] = f2b(acc[n]);
            else         xr[(long)node * HID + cc] = acc[n] + bias;
        }
    }
}

// ---- fused: agg1 gather-sum(bf16) + LR + h@[Wl2|Wr2] -> hl(bf16), hr(fp32) ----
// 8 lanes per node (li=lane&7 -> features 8li..8li+7 via one uint4),
// 8 nodes per wave, 8 gathers in flight per group.
__global__ __launch_bounds__(256) void agg_mid_kernel(
    const int* __restrict__ rowptr, const int* __restrict__ srcs,
    const uint4* __restrict__ xlq,   // row n at xlq + n*8
    const float* __restrict__ xr,
    const float* __restrict__ Wl2, const float* __restrict__ Wr2,
    const float* __restrict__ b2,
    uint4* __restrict__ hlq,         // row n at hlq + n*4
    float* __restrict__ hr, int N) {
    __shared__ float Wc[HID][HID];   // 16 KB: cols 0..31 = Wl2, 32..63 = Wr2
    for (int i = threadIdx.x; i < HID * HID; i += 256) {
        int k = i >> 6, c = i & 63;
        Wc[k][c] = (c < OUT_DIM) ? Wl2[k * OUT_DIM + c]
                                 : Wr2[k * OUT_DIM + (c - OUT_DIM)];
    }
    __syncthreads();
    const int lane  = threadIdx.x & 63;
    const int li    = lane & 7;        // feature octet index
    const int gbase = lane & 56;       // group g * 8
    const int wave  = (blockIdx.x << 2) + (threadIdx.x >> 6);
    const int n     = wave * 8 + (lane >> 3);
    if (n >= N) return;                // group-uniform
    const int rp = rowptr[n];
    const int d  = rowptr[n + 1] - rp;
    float acc[8] = {};
    int j = 0;
    while (j + 8 <= d) {               // full batches of 8 edges per group
        int sidb = srcs[rp + j + li];
#pragma unroll
        for (int t = 0; t < 8; ++t) {
            int s = __shfl(sidb, gbase + t);
            uint4 u = xlq[(long)s * 8 + li];
            acc[0] += blo(u.x); acc[1] += bhi(u.x);
            acc[2] += blo(u.y); acc[3] += bhi(u.y);
            acc[4] += blo(u.z); acc[5] += bhi(u.z);
            acc[6] += blo(u.w); acc[7] += bhi(u.w);
        }
        j += 8;
    }
    int r = d - j;                     // 0..7 remainder
    if (r > 0) {
        int sidb = srcs[rp + j + ((li < r) ? li : 0)];
#pragma unroll
        for (int t = 0; t < 7; ++t) {
            if (t < r) {
                int s = __shfl(sidb, gbase + t);
                uint4 u = xlq[(long)s * 8 + li];
                acc[0] += blo(u.x); acc[1] += bhi(u.x);
                acc[2] += blo(u.y); acc[3] += bhi(u.y);
                acc[4] += blo(u.z); acc[5] += bhi(u.z);
                acc[6] += blo(u.w); acc[7] += bhi(u.w);
            }
        }
    }
    const float dinv = (d > 0) ? (1.f / (float)d) : 1.f;
    float4 xrA = *reinterpret_cast<const float4*>(&xr[(long)n * HID + 8 * li]);
    float4 xrB = *reinterpret_cast<const float4*>(&xr[(long)n * HID + 8 * li + 4]);
    float h[8];
    h[0] = fmaf(acc[0], dinv, xrA.x); h[1] = fmaf(acc[1], dinv, xrA.y);
    h[2] = fmaf(acc[2], dinv, xrA.z); h[3] = fmaf(acc[3], dinv, xrA.w);
    h[4] = fmaf(acc[4], dinv, xrB.x); h[5] = fmaf(acc[5], dinv, xrB.y);
    h[6] = fmaf(acc[6], dinv, xrB.z); h[7] = fmaf(acc[7], dinv, xrB.w);
#pragma unroll
    for (int t = 0; t < 8; ++t) h[t] = (h[t] > 0.f) ? h[t] : SLOPE * h[t];
    // projection: lane computes out cols c = 8li..8li+7 for its node;
    // h[k] of this node lives at lane gbase + (k>>3), register k&7.
    float o[8] = {};
#pragma unroll
    for (int k = 0; k < HID; ++k) {
        float hk = __shfl(h[k & 7], gbase + (k >> 3));
        float4 wA = *reinterpret_cast<const float4*>(&Wc[k][8 * li]);
        float4 wB = *reinterpret_cast<const float4*>(&Wc[k][8 * li + 4]);
        o[0] = fmaf(hk, wA.x, o[0]); o[1] = fmaf(hk, wA.y, o[1]);
        o[2] = fmaf(hk, wA.z, o[2]); o[3] = fmaf(hk, wA.w, o[3]);
        o[4] = fmaf(hk, wB.x, o[4]); o[5] = fmaf(hk, wB.y, o[5]);
        o[6] = fmaf(hk, wB.z, o[6]); o[7] = fmaf(hk, wB.w, o[7]);
    }
    if (li < 4) {                      // hl cols 0..31, bf16 packed
        uint4 pk;
        pk.x = pack2(o[0], o[1]); pk.y = pack2(o[2], o[3]);
        pk.z = pack2(o[4], o[5]); pk.w = pack2(o[6], o[7]);
        hlq[(long)n * 4 + li] = pk;
    } else {                           // hr cols 0..31 (+b2), fp32
        int c0 = 8 * li - 32;          // 0,8,16,24
        float4 bA = *reinterpret_cast<const float4*>(&b2[c0]);
        float4 bB = *reinterpret_cast<const float4*>(&b2[c0 + 4]);
        float4 vA = {o[0] + bA.x, o[1] + bA.y, o[2] + bA.z, o[3] + bA.w};
        float4 vB = {o[4] + bB.x, o[5] + bB.y, o[6] + bB.z, o[7] + bB.w};
        *reinterpret_cast<float4*>(&hr[(long)n * OUT_DIM + c0]) = vA;
        *reinterpret_cast<float4*>(&hr[(long)n * OUT_DIM + c0 + 4]) = vB;
    }
}

// ---- fused: agg2 gather-sum(bf16) + LR -> z ----
// 4 lanes per node (li=lane&3 -> features 8li..8li+7), 16 nodes per wave.
__global__ __launch_bounds__(256) void agg2_final_kernel(
    const int* __restrict__ rowptr, const int* __restrict__ srcs,
    const uint4* __restrict__ hlq,   // row n at hlq + n*4
    const float* __restrict__ hr,
    float* __restrict__ z, int N) {
    const int lane  = threadIdx.x & 63;
    const int li    = lane & 3;
    const int gbase = lane & 60;       // group g * 4
    const int wave  = (blockIdx.x << 2) + (threadIdx.x >> 6);
    const int n     = wave * 16 + (lane >> 2);
    if (n >= N) return;                // group-uniform
    const int rp = rowptr[n];
    const int d  = rowptr[n + 1] - rp;
    float acc[8] = {};
    int j = 0;
    while (j + 8 <= d) {
        int sA = srcs[rp + j + li];
        int sB = srcs[rp + j + 4 + li];
#pragma unroll
        for (int t = 0; t < 4; ++t) {
            int s0 = __shfl(sA, gbase + t);
            int s1 = __shfl(sB, gbase + t);
            uint4 u0 = hlq[(long)s0 * 4 + li];
            uint4 u1 = hlq[(long)s1 * 4 + li];
            acc[0] += blo(u0.x); acc[1] += bhi(u0.x);
            acc[2] += blo(u0.y); acc[3] += bhi(u0.y);
            acc[4] += blo(u0.z); acc[5] += bhi(u0.z);
            acc[6] += blo(u0.w); acc[7] += bhi(u0.w);
            acc[0] += blo(u1.x); acc[1] += bhi(u1.x);
            acc[2] += blo(u1.y); acc[3] += bhi(u1.y);
            acc[4] += blo(u1.z); acc[5] += bhi(u1.z);
            acc[6] += blo(u1.w); acc[7] += bhi(u1.w);
        }
        j += 8;
    }
    int r = d - j;                     // 0..7
    if (r > 0) {
        int sA = srcs[rp + j + ((li < r) ? li : 0)];
        int sB = srcs[rp + j + ((4 + li < r) ? 4 + li : 0)];
#pragma unroll
        for (int t = 0; t < 4; ++t) {
            if (t < r) {
                int s = __shfl(sA, gbase + t);
                uint4 u = hlq[(long)s * 4 + li];
                acc[0] += blo(u.x); acc[1] += bhi(u.x);
                acc[2] += blo(u.y); acc[3] += bhi(u.y);
                acc[4] += blo(u.z); acc[5] += bhi(u.z);
                acc[6] += blo(u.w); acc[7] += bhi(u.w);
            }
            if (t + 4 < r) {
                int s = __shfl(sB, gbase + t);
                uint4 u = hlq[(long)s * 4 + li];
                acc[0] += blo(u.x); acc[1] += bhi(u.x);
                acc[2] += blo(u.y); acc[3] += bhi(u.y);
                acc[4] += blo(u.z); acc[5] += bhi(u.z);
                acc[6] += blo(u.w); acc[7] += bhi(u.w);
            }
        }
    }
    const float dinv = (d > 0) ? (1.f / (float)d) : 1.f;
    float4 hA = *reinterpret_cast<const float4*>(&hr[(long)n * OUT_DIM + 8 * li]);
    float4 hB = *reinterpret_cast<const float4*>(&hr[(long)n * OUT_DIM + 8 * li + 4]);
    float4 vA, vB;
    vA.x = fmaf(acc[0], dinv, hA.x); vA.y = fmaf(acc[1], dinv, hA.y);
    vA.z = fmaf(acc[2], dinv, hA.z); vA.w = fmaf(acc[3], dinv, hA.w);
    vB.x = fmaf(acc[4], dinv, hB.x); vB.y = fmaf(acc[5], dinv, hB.y);
    vB.z = fmaf(acc[6], dinv, hB.z); vB.w = fmaf(acc[7], dinv, hB.w);
    vA.x = (vA.x > 0.f) ? vA.x : SLOPE * vA.x;
    vA.y = (vA.y > 0.f) ? vA.y : SLOPE * vA.y;
    vA.z = (vA.z > 0.f) ? vA.z : SLOPE * vA.z;
    vA.w = (vA.w > 0.f) ? vA.w : SLOPE * vA.w;
    vB.x = (vB.x > 0.f) ? vB.x : SLOPE * vB.x;
    vB.y = (vB.y > 0.f) ? vB.y : SLOPE * vB.y;
    vB.z = (vB.z > 0.f) ? vB.z : SLOPE * vB.z;
    vB.w = (vB.w > 0.f) ? vB.w : SLOPE * vB.w;
    *reinterpret_cast<float4*>(&z[(long)n * OUT_DIM + 8 * li]) = vA;
    *reinterpret_cast<float4*>(&z[(long)n * OUT_DIM + 8 * li + 4]) = vB;
}

extern "C" void kernel_launch(void* const* d_in, const int* in_sizes, int n_in,
                              void* d_out, int out_size, void* d_ws, size_t ws_size,
                              hipStream_t stream) {
    const float* x   = (const float*)d_in[0];
    const int*   ei  = (const int*)d_in[1];
    const float* Wl1 = (const float*)d_in[2];
    const float* Wr1 = (const float*)d_in[3];
    const float* b1  = (const float*)d_in[4];
    const float* Wl2 = (const float*)d_in[5];
    const float* Wr2 = (const float*)d_in[6];
    const float* b2  = (const float*)d_in[7];

    const int N = in_sizes[0] / IN_DIM;
    const int E = in_sizes[1] / 2;
    const int* src = ei;
    const int* dst = ei + E;
    const int nb = (N + 255) / 256;

    char* p = (char*)d_ws;
    int* deg     = (int*)p;            p += sizeof(int) * N;
    int* rp_part = (int*)p;            p += sizeof(int) * N;
    int* rowptr  = (int*)p;            p += sizeof(int) * (N + 4);  // 16B-aligned size
    int* cursor  = (int*)p;            p += sizeof(int) * N;
    int* bsum    = (int*)p;            p += sizeof(int) * 512;
    int* boff    = (int*)p;            p += sizeof(int) * 512;
    int* srcs    = (int*)p;            p += sizeof(int) * E;
    ushort16* xl = (ushort16*)p;       p += sizeof(ushort16) * (size_t)N * HID;
    float* xr    = (float*)p;          p += sizeof(float) * (size_t)N * HID;
    ushort16* hl = (ushort16*)p;       p += sizeof(ushort16) * (size_t)N * OUT_DIM;
    float* hr    = (float*)p;          p += sizeof(float) * (size_t)N * OUT_DIM;

    hipMemsetAsync(deg, 0, sizeof(int) * N, stream);

    deg_kernel<<<(E + 255) / 256, 256, 0, stream>>>(dst, deg, E);
    scan_a<<<nb, 256, 0, stream>>>(deg, rp_part, bsum, N);
    scan_b<<<1, 512, 0, stream>>>(bsum, boff, nb);
    scan_c<<<(N + 255) / 256, 256, 0, stream>>>(rp_part, boff, deg, rowptr, cursor, N);
    bin_kernel<<<(E + 255) / 256, 256, 0, stream>>>(src, dst, cursor, srcs, E);
    gemm1_kernel<<<(N + 7) / 8, 128, 0, stream>>>(x, Wl1, Wr1, b1, xl, xr, N);
    agg_mid_kernel<<<(N + 31) / 32, 256, 0, stream>>>(rowptr, srcs, (const uint4*)xl, xr,
                                                      Wl2, Wr2, b2, (uint4*)hl, hr, N);
    agg2_final_kernel<<<(N + 63) / 64, 256, 0, stream>>>(rowptr, srcs, (const uint4*)hl, hr,
                                                         (float*)d_out, N);
}

// Round 5
// 320.333 us; speedup vs baseline: 2.5699x; 1.4494x over previous
//
#include <hip/hip_runtime.h>

// SAGEConv x2 forward. CSR built via bucketed two-pass binning (no write
// amplification). Aggregation: sub-wave groups, bf16 uint4 gather payloads.

constexpr int IN_DIM  = 128;
constexpr int HID     = 64;
constexpr int OUT_DIM = 32;
constexpr float SLOPE = 0.1f;
constexpr int NPB_SHIFT = 8;     // 256 nodes per bucket
constexpr int NBMAX = 512;       // max buckets (N <= 131072)
constexpr int CHUNK = 4096;      // edges per partition block

typedef unsigned int uint32;
typedef unsigned short ushort16;

__device__ inline float blo(uint32 u) { return __uint_as_float(u << 16); }
__device__ inline float bhi(uint32 u) { return __uint_as_float(u & 0xffff0000u); }
__device__ inline ushort16 f2b(float f) {
    uint32 u = __float_as_uint(f);
    u += 0x7fffu + ((u >> 16) & 1u);   // round-to-nearest-even
    return (ushort16)(u >> 16);
}
__device__ inline uint32 pack2(float lo, float hi) {
    return (uint32)f2b(lo) | ((uint32)f2b(hi) << 16);
}

__global__ __launch_bounds__(256) void bucket_hist_kernel(
    const int* __restrict__ dst, int* __restrict__ bhist, int E) {
    __shared__ int bh[NBMAX];
    for (int i = threadIdx.x; i < NBMAX; i += 256) bh[i] = 0;
    __syncthreads();
    for (int e = blockIdx.x * 256 + threadIdx.x; e < E; e += gridDim.x * 256)
        atomicAdd(&bh[dst[e] >> NPB_SHIFT], 1);
    __syncthreads();
    for (int b = threadIdx.x; b < NBMAX; b += 256)
        if (bh[b]) atomicAdd(&bhist[b], bh[b]);
}

__global__ __launch_bounds__(512) void bucket_scan_kernel(
    const int* __restrict__ bhist, int* __restrict__ ebase,
    int* __restrict__ pbase, int* __restrict__ bcur,
    int* __restrict__ rowptr, int NB, int N, int E) {
    __shared__ int s1[512], s2[512];
    const int t = threadIdx.x;
    int bh = (t < NB) ? bhist[t] : 0;
    int pd = (bh + 15) & ~15;
    s1[t] = bh; s2[t] = pd; __syncthreads();
    for (int off = 1; off < 512; off <<= 1) {
        int a = (t >= off) ? s1[t - off] : 0;
        int b = (t >= off) ? s2[t - off] : 0;
        __syncthreads();
        s1[t] += a; s2[t] += b;
        __syncthreads();
    }
    ebase[t] = s1[t] - bh;
    pbase[t] = s2[t] - pd;
    bcur[t]  = s2[t] - pd;
    if (t == 0) rowptr[N] = E;
}

__global__ __launch_bounds__(256) void partition_kernel(
    const int* __restrict__ src, const int* __restrict__ dst,
    int* __restrict__ bcur, uint32* __restrict__ pairs, int E, int NB) {
    __shared__ int hist[NBMAX], loff[NBMAX], cur[NBMAX];
    __shared__ int s[256];
    __shared__ uint32 stage[CHUNK];
    const int tid = threadIdx.x;
    const int e0  = blockIdx.x * CHUNK;
    const int cnt = min(CHUNK, E - e0);
    for (int i = tid; i < NBMAX; i += 256) hist[i] = 0;
    __syncthreads();
    int sreg[16], dreg[16];
#pragma unroll
    for (int k = 0; k < 16; ++k) {
        int i = tid + k * 256;
        if (i < cnt) {
            sreg[k] = src[e0 + i];
            dreg[k] = dst[e0 + i];
            atomicAdd(&hist[dreg[k] >> NPB_SHIFT], 1);
        }
    }
    __syncthreads();
    int a0 = hist[2 * tid], a1 = hist[2 * tid + 1];
    s[tid] = a0 + a1; __syncthreads();
    for (int off = 1; off < 256; off <<= 1) {
        int t = (tid >= off) ? s[tid - off] : 0;
        __syncthreads();
        s[tid] += t;
        __syncthreads();
    }
    int ex = s[tid] - (a0 + a1);
    loff[2 * tid] = ex;      loff[2 * tid + 1] = ex + a0;
    cur[2 * tid]  = ex;      cur[2 * tid + 1]  = ex + a0;
    __syncthreads();
#pragma unroll
    for (int k = 0; k < 16; ++k) {
        int i = tid + k * 256;
        if (i < cnt) {
            int b = dreg[k] >> NPB_SHIFT;
            int pos = atomicAdd(&cur[b], 1);
            stage[pos] = (uint32)sreg[k] | ((uint32)(dreg[k] & 255) << 24);
        }
    }
    __syncthreads();
    for (int b = tid; b < NB; b += 256) {
        int cb = hist[b];
        if (cb) {
            int g  = atomicAdd(&bcur[b], cb);
            int lb = loff[b];
            for (int k = 0; k < cb; ++k) pairs[g + k] = stage[lb + k];
        }
    }
}

__global__ __launch_bounds__(256) void fine_bin_kernel(
    const uint32* __restrict__ pairs, const int* __restrict__ bhist,
    const int* __restrict__ ebase, const int* __restrict__ pbase,
    int* __restrict__ rowptr, int* __restrict__ srcs, int N) {
    __shared__ int h2[256], cur[256], s[256];
    const int tid  = threadIdx.x;
    const int b    = blockIdx.x;
    const int n0   = b << NPB_SHIFT;
    const int base = pbase[b];
    const int sz   = bhist[b];
    h2[tid] = 0;
    __syncthreads();
    for (int i = tid; i < sz; i += 256)
        atomicAdd(&h2[pairs[base + i] >> 24], 1);
    __syncthreads();
    int v = h2[tid]; s[tid] = v; __syncthreads();
    for (int off = 1; off < 256; off <<= 1) {
        int t = (tid >= off) ? s[tid - off] : 0;
        __syncthreads();
        s[tid] += t;
        __syncthreads();
    }
    int rp = ebase[b] + s[tid] - v;
    int n  = n0 + tid;
    if (n < N) rowptr[n] = rp;
    cur[tid] = rp;
    __syncthreads();
    for (int i = tid; i < sz; i += 256) {
        uint32 u = pairs[base + i];
        int p = atomicAdd(&cur[u >> 24], 1);
        srcs[p] = (int)(u & 0xFFFFFFu);
    }
}

__global__ __launch_bounds__(128) void gemm1_kernel(
    const float* __restrict__ x, const float* __restrict__ Wl,
    const float* __restrict__ Wr, const float* __restrict__ b1,
    ushort16* __restrict__ xl, float* __restrict__ xr, int N) {
    __shared__ float xs[8][IN_DIM];
    const int c  = threadIdx.x;
    const int n0 = blockIdx.x * 8;
#pragma unroll
    for (int n = 0; n < 8; ++n) {
        int node = n0 + n;
        xs[n][c] = (node < N) ? x[(long)node * IN_DIM + c] : 0.f;
    }
    __syncthreads();
    const float* W = (c < HID) ? Wl : Wr;
    const int cc = c & (HID - 1);
    float acc[8] = {};
    for (int k = 0; k < IN_DIM; k += 4) {
        float w0 = W[(k + 0) * HID + cc];
        float w1 = W[(k + 1) * HID + cc];
        float w2 = W[(k + 2) * HID + cc];
        float w3 = W[(k + 3) * HID + cc];
#pragma unroll
        for (int n = 0; n < 8; ++n) {
            float4 xv = *reinterpret_cast<const float4*>(&xs[n][k]);
            acc[n] = fmaf(xv.x, w0, acc[n]);
            acc[n] = fmaf(xv.y, w1, acc[n]);
            acc[n] = fmaf(xv.z, w2, acc[n]);
            acc[n] = fmaf(xv.w, w3, acc[n]);
        }
    }
    const float bias = (c >= HID) ? b1[cc] : 0.f;
#pragma unroll
    for (int n = 0; n < 8; ++n) {
        int node = n0 + n;
        if (node < N) {
            if (c < HID) xl[(long)node * HID + cc] = f2b(acc[n]);
            else         xr[(long)node * HID + cc] = acc[n] + bias;
        }
    }
}

__global__ __launch_bounds__(256) void agg_mid_kernel(
    const int* __restrict__ rowptr, const int* __restrict__ srcs,
    const uint4* __restrict__ xlq,
    const float* __restrict__ xr,
    const float* __restrict__ Wl2, const float* __restrict__ Wr2,
    const float* __restrict__ b2,
    uint4* __restrict__ hlq,
    float* __restrict__ hr, int N) {
    __shared__ float Wc[HID][HID];
    for (int i = threadIdx.x; i < HID * HID; i += 256) {
        int k = i >> 6, c = i & 63;
        Wc[k][c] = (c < OUT_DIM) ? Wl2[k * OUT_DIM + c]
                                 : Wr2[k * OUT_DIM + (c - OUT_DIM)];
    }
    __syncthreads();
    const int lane  = threadIdx.x & 63;
    const int li    = lane & 7;
    const int gbase = lane & 56;
    const int wave  = (blockIdx.x << 2) + (threadIdx.x >> 6);
    const int n     = wave * 8 + (lane >> 3);
    if (n >= N) return;
    const int rp = rowptr[n];
    const int d  = rowptr[n + 1] - rp;
    float acc[8] = {};
    int j = 0;
    while (j + 8 <= d) {
        int sidb = srcs[rp + j + li];
#pragma unroll
        for (int t = 0; t < 8; ++t) {
            int s = __shfl(sidb, gbase + t);
            uint4 u = xlq[(long)s * 8 + li];
            acc[0] += blo(u.x); acc[1] += bhi(u.x);
            acc[2] += blo(u.y); acc[3] += bhi(u.y);
            acc[4] += blo(u.z); acc[5] += bhi(u.z);
            acc[6] += blo(u.w); acc[7] += bhi(u.w);
        }
        j += 8;
    }
    int r = d - j;
    if (r > 0) {
        int sidb = srcs[rp + j + ((li < r) ? li : 0)];
#pragma unroll
        for (int t = 0; t < 7; ++t) {
            if (t < r) {
                int s = __shfl(sidb, gbase + t);
                uint4 u = xlq[(long)s * 8 + li];
                acc[0] += blo(u.x); acc[1] += bhi(u.x);
                acc[2] += blo(u.y); acc[3] += bhi(u.y);
                acc[4] += blo(u.z); acc[5] += bhi(u.z);
                acc[6] += blo(u.w); acc[7] += bhi(u.w);
            }
        }
    }
    const float dinv = (d > 0) ? (1.f / (float)d) : 1.f;
    float4 xrA = *reinterpret_cast<const float4*>(&xr[(long)n * HID + 8 * li]);
    float4 xrB = *reinterpret_cast<const float4*>(&xr[(long)n * HID + 8 * li + 4]);
    float h[8];
    h[0] = fmaf(acc[0], dinv, xrA.x); h[1] = fmaf(acc[1], dinv, xrA.y);
    h[2] = fmaf(acc[2], dinv, xrA.z); h[3] = fmaf(acc[3], dinv, xrA.w);
    h[4] = fmaf(acc[4], dinv, xrB.x); h[5] = fmaf(acc[5], dinv, xrB.y);
    h[6] = fmaf(acc[6], dinv, xrB.z); h[7] = fmaf(acc[7], dinv, xrB.w);
#pragma unroll
    for (int t = 0; t < 8; ++t) h[t] = (h[t] > 0.f) ? h[t] : SLOPE * h[t];
    float o[8] = {};
#pragma unroll
    for (int k = 0; k < HID; ++k) {
        float hk = __shfl(h[k & 7], gbase + (k >> 3));
        float4 wA = *reinterpret_cast<const float4*>(&Wc[k][8 * li]);
        float4 wB = *reinterpret_cast<const float4*>(&Wc[k][8 * li + 4]);
        o[0] = fmaf(hk, wA.x, o[0]); o[1] = fmaf(hk, wA.y, o[1]);
        o[2] = fmaf(hk, wA.z, o[2]); o[3] = fmaf(hk, wA.w, o[3]);
        o[4] = fmaf(hk, wB.x, o[4]); o[5] = fmaf(hk, wB.y, o[5]);
        o[6] = fmaf(hk, wB.z, o[6]); o[7] = fmaf(hk, wB.w, o[7]);
    }
    if (li < 4) {
        uint4 pk;
        pk.x = pack2(o[0], o[1]); pk.y = pack2(o[2], o[3]);
        pk.z = pack2(o[4], o[5]); pk.w = pack2(o[6], o[7]);
        hlq[(long)n * 4 + li] = pk;
    } else {
        int c0 = 8 * li - 32;
        float4 bA = *reinterpret_cast<const float4*>(&b2[c0]);
        float4 bB = *reinterpret_cast<const float4*>(&b2[c0 + 4]);
        float4 vA = {o[0] + bA.x, o[1] + bA.y, o[2] + bA.z, o[3] + bA.w};
        float4 vB = {o[4] + bB.x, o[5] + bB.y, o[6] + bB.z, o[7] + bB.w};
        *reinterpret_cast<float4*>(&hr[(long)n * OUT_DIM + c0]) = vA;
        *reinterpret_cast<float4*>(&hr[(long)n * OUT_DIM + c0 + 4]) = vB;
    }
}

__global__ __launch_bounds__(256) void agg2_final_kernel(
    const int* __restrict__ rowptr, const int* __restrict__ srcs,
    const uint4* __restrict__ hlq,
    const float* __restrict__ hr,
    float* __restrict__ z, int N) {
    const int lane  = threadIdx.x & 63;
    const int li    = lane & 3;
    const int gbase = lane & 60;
    const int wave  = (blockIdx.x << 2) + (threadIdx.x >> 6);
    const int n     = wave * 16 + (lane >> 2);
    if (n >= N) return;
    const int rp = rowptr[n];
    const int d  = rowptr[n + 1] - rp;
    float acc[8] = {};
    int j = 0;
    while (j + 8 <= d) {
        int sA = srcs[rp + j + li];
        int sB = srcs[rp + j + 4 + li];
#pragma unroll
        for (int t = 0; t < 4; ++t) {
            int s0 = __shfl(sA, gbase + t);
            int s1 = __shfl(sB, gbase + t);
            uint4 u0 = hlq[(long)s0 * 4 + li];
            uint4 u1 = hlq[(long)s1 * 4 + li];
            acc[0] += blo(u0.x); acc[1] += bhi(u0.x);
            acc[2] += blo(u0.y); acc[3] += bhi(u0.y);
            acc[4] += blo(u0.z); acc[5] += bhi(u0.z);
            acc[6] += blo(u0.w); acc[7] += bhi(u0.w);
            acc[0] += blo(u1.x); acc[1] += bhi(u1.x);
            acc[2] += blo(u1.y); acc[3] += bhi(u1.y);
            acc[4] += blo(u1.z); acc[5] += bhi(u1.z);
            acc[6] += blo(u1.w); acc[7] += bhi(u1.w);
        }
        j += 8;
    }
    int r = d - j;
    if (r > 0) {
        int sA = srcs[rp + j + ((li < r) ? li : 0)];
        int sB = srcs[rp + j + ((4 + li < r) ? 4 + li : 0)];
#pragma unroll
        for (int t = 0; t < 4; ++t) {
            if (t < r) {
                int s = __shfl(sA, gbase + t);
                uint4 u = hlq[(long)s * 4 + li];
                acc[0] += blo(u.x); acc[1] += bhi(u.x);
                acc[2] += blo(u.y); acc[3] += bhi(u.y);
                acc[4] += blo(u.z); acc[5] += bhi(u.z);
                acc[6] += blo(u.w); acc[7] += bhi(u.w);
            }
            if (t + 4 < r) {
                int s = __shfl(sB, gbase + t);
                uint4 u = hlq[(long)s * 4 + li];
                acc[0] += blo(u.x); acc[1] += bhi(u.x);
                acc[2] += blo(u.y); acc[3] += bhi(u.y);
                acc[4] += blo(u.z); acc[5] += bhi(u.z);
                acc[6] += blo(u.w); acc[7] += bhi(u.w);
            }
        }
    }
    const float dinv = (d > 0) ? (1.f / (float)d) : 1.f;
    float4 hA = *reinterpret_cast<const float4*>(&hr[(long)n * OUT_DIM + 8 * li]);
    float4 hB = *reinterpret_cast<const float4*>(&hr[(long)n * OUT_DIM + 8 * li + 4]);
    float4 vA, vB;
    vA.x = fmaf(acc[0], dinv, hA.x); vA.y = fmaf(acc[1], dinv, hA.y);
    vA.z = fmaf(acc[2], dinv, hA.z); vA.w = fmaf(acc[3], dinv, hA.w);
    vB.x = fmaf(acc[4], dinv, hB.x); vB.y = fmaf(acc[5], dinv, hB.y);
    vB.z = fmaf(acc[6], dinv, hB.z); vB.w = fmaf(acc[7], dinv, hB.w);
    vA.x = (vA.x > 0.f) ? vA.x : SLOPE * vA.x;
    vA.y = (vA.y > 0.f) ? vA.y : SLOPE * vA.y;
    vA.z = (vA.z > 0.f) ? vA.z : SLOPE * vA.z;
    vA.w = (vA.w > 0.f) ? vA.w : SLOPE * vA.w;
    vB.x = (vB.x > 0.f) ? vB.x : SLOPE * vB.x;
    vB.y = (vB.y > 0.f) ? vB.y : SLOPE * vB.y;
    vB.z = (vB.z > 0.f) ? vB.z : SLOPE * vB.z;
    vB.w = (vB.w > 0.f) ? vB.w : SLOPE * vB.w;
    *reinterpret_cast<float4*>(&z[(long)n * OUT_DIM + 8 * li]) = vA;
    *reinterpret_cast<float4*>(&z[(long)n * OUT_DIM + 8 * li + 4]) = vB;
}

extern "C" void kernel_launch(void* const* d_in, const int* in_sizes, int n_in,
                              void* d_out, int out_size, void* d_ws, size_t ws_size,
                              hipStream_t stream) {
    const float* x   = (const float*)d_in[0];
    const int*   ei  = (const int*)d_in[1];
    const float* Wl1 = (const float*)d_in[2];
    const float* Wr1 = (const float*)d_in[3];
    const float* b1  = (const float*)d_in[4];
    const float* Wl2 = (const float*)d_in[5];
    const float* Wr2 = (const float*)d_in[6];
    const float* b2  = (const float*)d_in[7];

    const int N = in_sizes[0] / IN_DIM;
    const int E = in_sizes[1] / 2;
    const int* src = ei;
    const int* dst = ei + E;
    const int NB = (N + 255) >> NPB_SHIFT;   // buckets (<= 512)

    char* p = (char*)d_ws;
    int* bhist    = (int*)p;           p += sizeof(int) * NBMAX;
    int* ebase    = (int*)p;           p += sizeof(int) * NBMAX;
    int* pbase    = (int*)p;           p += sizeof(int) * NBMAX;
    int* bcur     = (int*)p;           p += sizeof(int) * NBMAX;
    int* rowptr   = (int*)p;           p += sizeof(int) * (N + 4);
    uint32* pairs = (uint32*)p;        p += sizeof(uint32) * ((size_t)E + 16 * NBMAX);
    int* srcs     = (int*)p;           p += sizeof(int) * E;
    ushort16* xl  = (ushort16*)p;      p += sizeof(ushort16) * (size_t)N * HID;
    float* xr     = (float*)p;         p += sizeof(float) * (size_t)N * HID;
    ushort16* hl  = (ushort16*)p;      p += sizeof(ushort16) * (size_t)N * OUT_DIM;
    float* hr     = (float*)p;         p += sizeof(float) * (size_t)N * OUT_DIM;

    hipMemsetAsync(bhist, 0, sizeof(int) * NBMAX, stream);

    bucket_hist_kernel<<<512, 256, 0, stream>>>(dst, bhist, E);
    bucket_scan_kernel<<<1, 512, 0, stream>>>(bhist, ebase, pbase, bcur, rowptr, NB, N, E);
    partition_kernel<<<(E + CHUNK - 1) / CHUNK, 256, 0, stream>>>(src, dst, bcur, pairs, E, NB);
    fine_bin_kernel<<<NB, 256, 0, stream>>>(pairs, bhist, ebase, pbase, rowptr, srcs, N);
    gemm1_kernel<<<(N + 7) / 8, 128, 0, stream>>>(x, Wl1, Wr1, b1, xl, xr, N);
    agg_mid_kernel<<<(N + 31) / 32, 256, 0, stream>>>(rowptr, srcs, (const uint4*)xl, xr,
                                                      Wl2, Wr2, b2, (uint4*)hl, hr, N);
    agg2_final_kernel<<<(N + 63) / 64, 256, 0, stream>>>(rowptr, srcs, (const uint4*)hl, hr,
                                                         (float*)d_out, N);
}

// Round 6
// 279.030 us; speedup vs baseline: 2.9503x; 1.1480x over previous
//
#include <hip/hip_runtime.h>

// SAGEConv x2 forward. CSR built via bucketed two-pass binning (no write
// amplification). gemm1 runs on MFMA (bf16 in, fp32 acc). Aggregation:
// sub-wave groups, bf16 uint4 gather payloads.

constexpr int IN_DIM  = 128;
constexpr int HID     = 64;
constexpr int OUT_DIM = 32;
constexpr float SLOPE = 0.1f;
constexpr int NPB_SHIFT = 8;     // 256 nodes per bucket
constexpr int NBMAX = 512;       // max buckets (N <= 131072)
constexpr int CHUNK = 4096;      // edges per partition block

typedef unsigned int uint32;
typedef unsigned short ushort16;

__device__ inline float blo(uint32 u) { return __uint_as_float(u << 16); }
__device__ inline float bhi(uint32 u) { return __uint_as_float(u & 0xffff0000u); }
__device__ inline ushort16 f2b(float f) {
    uint32 u = __float_as_uint(f);
    u += 0x7fffu + ((u >> 16) & 1u);   // round-to-nearest-even
    return (ushort16)(u >> 16);
}
__device__ inline uint32 pack2(float lo, float hi) {
    return (uint32)f2b(lo) | ((uint32)f2b(hi) << 16);
}

__global__ __launch_bounds__(256) void bucket_hist_kernel(
    const int* __restrict__ dst, int* __restrict__ bhist, int E) {
    __shared__ int bh[NBMAX];
    for (int i = threadIdx.x; i < NBMAX; i += 256) bh[i] = 0;
    __syncthreads();
    for (int e = blockIdx.x * 256 + threadIdx.x; e < E; e += gridDim.x * 256)
        atomicAdd(&bh[dst[e] >> NPB_SHIFT], 1);
    __syncthreads();
    for (int b = threadIdx.x; b < NBMAX; b += 256)
        if (bh[b]) atomicAdd(&bhist[b], bh[b]);
}

__global__ __launch_bounds__(512) void bucket_scan_kernel(
    const int* __restrict__ bhist, int* __restrict__ ebase,
    int* __restrict__ pbase, int* __restrict__ bcur,
    int* __restrict__ rowptr, int NB, int N, int E) {
    __shared__ int s1[512], s2[512];
    const int t = threadIdx.x;
    int bh = (t < NB) ? bhist[t] : 0;
    int pd = (bh + 15) & ~15;
    s1[t] = bh; s2[t] = pd; __syncthreads();
    for (int off = 1; off < 512; off <<= 1) {
        int a = (t >= off) ? s1[t - off] : 0;
        int b = (t >= off) ? s2[t - off] : 0;
        __syncthreads();
        s1[t] += a; s2[t] += b;
        __syncthreads();
    }
    ebase[t] = s1[t] - bh;
    pbase[t] = s2[t] - pd;
    bcur[t]  = s2[t] - pd;
    if (t == 0) rowptr[N] = E;
}

__global__ __launch_bounds__(256) void partition_kernel(
    const int* __restrict__ src, const int* __restrict__ dst,
    int* __restrict__ bcur, uint32* __restrict__ pairs, int E, int NB) {
    __shared__ int hist[NBMAX], loff[NBMAX], cur[NBMAX];
    __shared__ int s[256];
    __shared__ uint32 stage[CHUNK];
    const int tid = threadIdx.x;
    const int e0  = blockIdx.x * CHUNK;
    const int cnt = min(CHUNK, E - e0);
    for (int i = tid; i < NBMAX; i += 256) hist[i] = 0;
    __syncthreads();
    int sreg[16], dreg[16];
#pragma unroll
    for (int k = 0; k < 16; ++k) {
        int i = tid + k * 256;
        if (i < cnt) {
            sreg[k] = src[e0 + i];
            dreg[k] = dst[e0 + i];
            atomicAdd(&hist[dreg[k] >> NPB_SHIFT], 1);
        }
    }
    __syncthreads();
    int a0 = hist[2 * tid], a1 = hist[2 * tid + 1];
    s[tid] = a0 + a1; __syncthreads();
    for (int off = 1; off < 256; off <<= 1) {
        int t = (tid >= off) ? s[tid - off] : 0;
        __syncthreads();
        s[tid] += t;
        __syncthreads();
    }
    int ex = s[tid] - (a0 + a1);
    loff[2 * tid] = ex;      loff[2 * tid + 1] = ex + a0;
    cur[2 * tid]  = ex;      cur[2 * tid + 1]  = ex + a0;
    __syncthreads();
#pragma unroll
    for (int k = 0; k < 16; ++k) {
        int i = tid + k * 256;
        if (i < cnt) {
            int b = dreg[k] >> NPB_SHIFT;
            int pos = atomicAdd(&cur[b], 1);
            stage[pos] = (uint32)sreg[k] | ((uint32)(dreg[k] & 255) << 24);
        }
    }
    __syncthreads();
    for (int b = tid; b < NB; b += 256) {
        int cb = hist[b];
        if (cb) {
            int g  = atomicAdd(&bcur[b], cb);
            int lb = loff[b];
            for (int k = 0; k < cb; ++k) pairs[g + k] = stage[lb + k];
        }
    }
}

__global__ __launch_bounds__(256) void fine_bin_kernel(
    const uint32* __restrict__ pairs, const int* __restrict__ bhist,
    const int* __restrict__ ebase, const int* __restrict__ pbase,
    int* __restrict__ rowptr, int* __restrict__ srcs, int N) {
    __shared__ int h2[256], cur[256], s[256];
    const int tid  = threadIdx.x;
    const int b    = blockIdx.x;
    const int n0   = b << NPB_SHIFT;
    const int base = pbase[b];
    const int sz   = bhist[b];
    h2[tid] = 0;
    __syncthreads();
    for (int i = tid; i < sz; i += 256)
        atomicAdd(&h2[pairs[base + i] >> 24], 1);
    __syncthreads();
    int v = h2[tid]; s[tid] = v; __syncthreads();
    for (int off = 1; off < 256; off <<= 1) {
        int t = (tid >= off) ? s[tid - off] : 0;
        __syncthreads();
        s[tid] += t;
        __syncthreads();
    }
    int rp = ebase[b] + s[tid] - v;
    int n  = n0 + tid;
    if (n < N) rowptr[n] = rp;
    cur[tid] = rp;
    __syncthreads();
    for (int i = tid; i < sz; i += 256) {
        uint32 u = pairs[base + i];
        int p = atomicAdd(&cur[u >> 24], 1);
        srcs[p] = (int)(u & 0xFFFFFFu);
    }
}

// ---- MFMA gemm1: x[N,128] @ [Wl1|Wr1] -> xl bf16[N,64], xr fp32[N,64]+b1 ----
// Block = 64 nodes x 128 cols, 4 waves (16 nodes each). bf16 inputs, fp32 acc.
// LDS: A tile [64][136] ushort (pad +8 kills frag-read bank conflicts),
//      B = [Wl|Wr]^T [128][136] ushort.
__global__ __launch_bounds__(256) void gemm1_mfma_kernel(
    const float* __restrict__ x, const float* __restrict__ Wl,
    const float* __restrict__ Wr, const float* __restrict__ b1,
    ushort16* __restrict__ xl, float* __restrict__ xr, int N) {
    using frag = __attribute__((ext_vector_type(8))) short;   // 8 bf16
    using f32x4 = __attribute__((ext_vector_type(4))) float;
    constexpr int LDA = IN_DIM + 8;
    __shared__ ushort16 Ash[64][LDA];
    __shared__ ushort16 Bsh[128][LDA];
    const int tid = threadIdx.x;
    const int n0  = blockIdx.x * 64;
    // stage B^T: coalesced global read (lane = col), scattered LDS write
    {
        const int c = tid & 63;
        for (int k = tid >> 6; k < IN_DIM; k += 4) {
            Bsh[c][k]      = f2b(Wl[k * HID + c]);
            Bsh[c + 64][k] = f2b(Wr[k * HID + c]);
        }
    }
    // stage A: x rows -> bf16 (float4 coalesced reads)
    {
        const int lc  = (tid & 31) * 4;          // k offset
        for (int row = tid >> 5; row < 64; row += 8) {
            int node = n0 + row;
            float4 xv = (node < N)
                ? *reinterpret_cast<const float4*>(&x[(long)node * IN_DIM + lc])
                : float4{0.f, 0.f, 0.f, 0.f};
            ushort16 pk[4] = {f2b(xv.x), f2b(xv.y), f2b(xv.z), f2b(xv.w)};
            *reinterpret_cast<ushort2*>(&Ash[row][lc])     = ushort2{pk[0], pk[1]};
            *reinterpret_cast<ushort2*>(&Ash[row][lc + 2]) = ushort2{pk[2], pk[3]};
        }
    }
    __syncthreads();
    const int lane = tid & 63;
    const int m0   = (tid >> 6) * 16;            // wave's node stripe in block
    const int mlo  = lane & 15;
    const int qk   = lane >> 4;                  // 0..3
    frag Af[4];
#pragma unroll
    for (int kc = 0; kc < 4; ++kc)
        Af[kc] = *reinterpret_cast<const frag*>(&Ash[m0 + mlo][kc * 32 + qk * 8]);
#pragma unroll
    for (int ct = 0; ct < 8; ++ct) {
        f32x4 acc = {0.f, 0.f, 0.f, 0.f};
#pragma unroll
        for (int kc = 0; kc < 4; ++kc) {
            frag Bf = *reinterpret_cast<const frag*>(&Bsh[ct * 16 + mlo][kc * 32 + qk * 8]);
            acc = __builtin_amdgcn_mfma_f32_16x16x32_bf16(Af[kc], Bf, acc, 0, 0, 0);
        }
        const int col = ct * 16 + mlo;           // 0..127
#pragma unroll
        for (int r = 0; r < 4; ++r) {
            int node = n0 + m0 + qk * 4 + r;     // C/D: row=(lane>>4)*4+reg
            if (node < N) {
                if (col < HID) xl[(long)node * HID + col] = f2b(acc[r]);
                else           xr[(long)node * HID + (col - HID)] = acc[r] + b1[col - HID];
            }
        }
    }
}

__global__ __launch_bounds__(256) void agg_mid_kernel(
    const int* __restrict__ rowptr, const int* __restrict__ srcs,
    const uint4* __restrict__ xlq,
    const float* __restrict__ xr,
    const float* __restrict__ Wl2, const float* __restrict__ Wr2,
    const float* __restrict__ b2,
    uint4* __restrict__ hlq,
    float* __restrict__ hr, int N) {
    __shared__ float Wc[HID][HID];
    for (int i = threadIdx.x; i < HID * HID; i += 256) {
        int k = i >> 6, c = i & 63;
        Wc[k][c] = (c < OUT_DIM) ? Wl2[k * OUT_DIM + c]
                                 : Wr2[k * OUT_DIM + (c - OUT_DIM)];
    }
    __syncthreads();
    const int lane  = threadIdx.x & 63;
    const int li    = lane & 7;
    const int gbase = lane & 56;
    const int wave  = (blockIdx.x << 2) + (threadIdx.x >> 6);
    const int n     = wave * 8 + (lane >> 3);
    if (n >= N) return;
    const int rp = rowptr[n];
    const int d  = rowptr[n + 1] - rp;
    float acc[8] = {};
    int j = 0;
    while (j + 8 <= d) {
        int sidb = srcs[rp + j + li];
#pragma unroll
        for (int t = 0; t < 8; ++t) {
            int s = __shfl(sidb, gbase + t);
            uint4 u = xlq[(long)s * 8 + li];
            acc[0] += blo(u.x); acc[1] += bhi(u.x);
            acc[2] += blo(u.y); acc[3] += bhi(u.y);
            acc[4] += blo(u.z); acc[5] += bhi(u.z);
            acc[6] += blo(u.w); acc[7] += bhi(u.w);
        }
        j += 8;
    }
    int r = d - j;
    if (r > 0) {
        int sidb = srcs[rp + j + ((li < r) ? li : 0)];
#pragma unroll
        for (int t = 0; t < 7; ++t) {
            if (t < r) {
                int s = __shfl(sidb, gbase + t);
                uint4 u = xlq[(long)s * 8 + li];
                acc[0] += blo(u.x); acc[1] += bhi(u.x);
                acc[2] += blo(u.y); acc[3] += bhi(u.y);
                acc[4] += blo(u.z); acc[5] += bhi(u.z);
                acc[6] += blo(u.w); acc[7] += bhi(u.w);
            }
        }
    }
    const float dinv = (d > 0) ? (1.f / (float)d) : 1.f;
    float4 xrA = *reinterpret_cast<const float4*>(&xr[(long)n * HID + 8 * li]);
    float4 xrB = *reinterpret_cast<const float4*>(&xr[(long)n * HID + 8 * li + 4]);
    float h[8];
    h[0] = fmaf(acc[0], dinv, xrA.x); h[1] = fmaf(acc[1], dinv, xrA.y);
    h[2] = fmaf(acc[2], dinv, xrA.z); h[3] = fmaf(acc[3], dinv, xrA.w);
    h[4] = fmaf(acc[4], dinv, xrB.x); h[5] = fmaf(acc[5], dinv, xrB.y);
    h[6] = fmaf(acc[6], dinv, xrB.z); h[7] = fmaf(acc[7], dinv, xrB.w);
#pragma unroll
    for (int t = 0; t < 8; ++t) h[t] = (h[t] > 0.f) ? h[t] : SLOPE * h[t];
    float o[8] = {};
#pragma unroll
    for (int k = 0; k < HID; ++k) {
        float hk = __shfl(h[k & 7], gbase + (k >> 3));
        float4 wA = *reinterpret_cast<const float4*>(&Wc[k][8 * li]);
        float4 wB = *reinterpret_cast<const float4*>(&Wc[k][8 * li + 4]);
        o[0] = fmaf(hk, wA.x, o[0]); o[1] = fmaf(hk, wA.y, o[1]);
        o[2] = fmaf(hk, wA.z, o[2]); o[3] = fmaf(hk, wA.w, o[3]);
        o[4] = fmaf(hk, wB.x, o[4]); o[5] = fmaf(hk, wB.y, o[5]);
        o[6] = fmaf(hk, wB.z, o[6]); o[7] = fmaf(hk, wB.w, o[7]);
    }
    if (li < 4) {
        uint4 pk;
        pk.x = pack2(o[0], o[1]); pk.y = pack2(o[2], o[3]);
        pk.z = pack2(o[4], o[5]); pk.w = pack2(o[6], o[7]);
        hlq[(long)n * 4 + li] = pk;
    } else {
        int c0 = 8 * li - 32;
        float4 bA = *reinterpret_cast<const float4*>(&b2[c0]);
        float4 bB = *reinterpret_cast<const float4*>(&b2[c0 + 4]);
        float4 vA = {o[0] + bA.x, o[1] + bA.y, o[2] + bA.z, o[3] + bA.w};
        float4 vB = {o[4] + bB.x, o[5] + bB.y, o[6] + bB.z, o[7] + bB.w};
        *reinterpret_cast<float4*>(&hr[(long)n * OUT_DIM + c0]) = vA;
        *reinterpret_cast<float4*>(&hr[(long)n * OUT_DIM + c0 + 4]) = vB;
    }
}

__global__ __launch_bounds__(256) void agg2_final_kernel(
    const int* __restrict__ rowptr, const int* __restrict__ srcs,
    const uint4* __restrict__ hlq,
    const float* __restrict__ hr,
    float* __restrict__ z, int N) {
    const int lane  = threadIdx.x & 63;
    const int li    = lane & 3;
    const int gbase = lane & 60;
    const int wave  = (blockIdx.x << 2) + (threadIdx.x >> 6);
    const int n     = wave * 16 + (lane >> 2);
    if (n >= N) return;
    const int rp = rowptr[n];
    const int d  = rowptr[n + 1] - rp;
    float acc[8] = {};
    int j = 0;
    while (j + 8 <= d) {
        int sA = srcs[rp + j + li];
        int sB = srcs[rp + j + 4 + li];
#pragma unroll
        for (int t = 0; t < 4; ++t) {
            int s0 = __shfl(sA, gbase + t);
            int s1 = __shfl(sB, gbase + t);
            uint4 u0 = hlq[(long)s0 * 4 + li];
            uint4 u1 = hlq[(long)s1 * 4 + li];
            acc[0] += blo(u0.x); acc[1] += bhi(u0.x);
            acc[2] += blo(u0.y); acc[3] += bhi(u0.y);
            acc[4] += blo(u0.z); acc[5] += bhi(u0.z);
            acc[6] += blo(u0.w); acc[7] += bhi(u0.w);
            acc[0] += blo(u1.x); acc[1] += bhi(u1.x);
            acc[2] += blo(u1.y); acc[3] += bhi(u1.y);
            acc[4] += blo(u1.z); acc[5] += bhi(u1.z);
            acc[6] += blo(u1.w); acc[7] += bhi(u1.w);
        }
        j += 8;
    }
    int r = d - j;
    if (r > 0) {
        int sA = srcs[rp + j + ((li < r) ? li : 0)];
        int sB = srcs[rp + j + ((4 + li < r) ? 4 + li : 0)];
#pragma unroll
        for (int t = 0; t < 4; ++t) {
            if (t < r) {
                int s = __shfl(sA, gbase + t);
                uint4 u = hlq[(long)s * 4 + li];
                acc[0] += blo(u.x); acc[1] += bhi(u.x);
                acc[2] += blo(u.y); acc[3] += bhi(u.y);
                acc[4] += blo(u.z); acc[5] += bhi(u.z);
                acc[6] += blo(u.w); acc[7] += bhi(u.w);
            }
            if (t + 4 < r) {
                int s = __shfl(sB, gbase + t);
                uint4 u = hlq[(long)s * 4 + li];
                acc[0] += blo(u.x); acc[1] += bhi(u.x);
                acc[2] += blo(u.y); acc[3] += bhi(u.y);
                acc[4] += blo(u.z); acc[5] += bhi(u.z);
                acc[6] += blo(u.w); acc[7] += bhi(u.w);
            }
        }
    }
    const float dinv = (d > 0) ? (1.f / (float)d) : 1.f;
    float4 hA = *reinterpret_cast<const float4*>(&hr[(long)n * OUT_DIM + 8 * li]);
    float4 hB = *reinterpret_cast<const float4*>(&hr[(long)n * OUT_DIM + 8 * li + 4]);
    float4 vA, vB;
    vA.x = fmaf(acc[0], dinv, hA.x); vA.y = fmaf(acc[1], dinv, hA.y);
    vA.z = fmaf(acc[2], dinv, hA.z); vA.w = fmaf(acc[3], dinv, hA.w);
    vB.x = fmaf(acc[4], dinv, hB.x); vB.y = fmaf(acc[5], dinv, hB.y);
    vB.z = fmaf(acc[6], dinv, hB.z); vB.w = fmaf(acc[7], dinv, hB.w);
    vA.x = (vA.x > 0.f) ? vA.x : SLOPE * vA.x;
    vA.y = (vA.y > 0.f) ? vA.y : SLOPE * vA.y;
    vA.z = (vA.z > 0.f) ? vA.z : SLOPE * vA.z;
    vA.w = (vA.w > 0.f) ? vA.w : SLOPE * vA.w;
    vB.x = (vB.x > 0.f) ? vB.x : SLOPE * vB.x;
    vB.y = (vB.y > 0.f) ? vB.y : SLOPE * vB.y;
    vB.z = (vB.z > 0.f) ? vB.z : SLOPE * vB.z;
    vB.w = (vB.w > 0.f) ? vB.w : SLOPE * vB.w;
    *reinterpret_cast<float4*>(&z[(long)n * OUT_DIM + 8 * li]) = vA;
    *reinterpret_cast<float4*>(&z[(long)n * OUT_DIM + 8 * li + 4]) = vB;
}

extern "C" void kernel_launch(void* const* d_in, const int* in_sizes, int n_in,
                              void* d_out, int out_size, void* d_ws, size_t ws_size,
                              hipStream_t stream) {
    const float* x   = (const float*)d_in[0];
    const int*   ei  = (const int*)d_in[1];
    const float* Wl1 = (const float*)d_in[2];
    const float* Wr1 = (const float*)d_in[3];
    const float* b1  = (const float*)d_in[4];
    const float* Wl2 = (const float*)d_in[5];
    const float* Wr2 = (const float*)d_in[6];
    const float* b2  = (const float*)d_in[7];

    const int N = in_sizes[0] / IN_DIM;
    const int E = in_sizes[1] / 2;
    const int* src = ei;
    const int* dst = ei + E;
    const int NB = (N + 255) >> NPB_SHIFT;   // buckets (<= 512)

    char* p = (char*)d_ws;
    int* bhist    = (int*)p;           p += sizeof(int) * NBMAX;
    int* ebase    = (int*)p;           p += sizeof(int) * NBMAX;
    int* pbase    = (int*)p;           p += sizeof(int) * NBMAX;
    int* bcur     = (int*)p;           p += sizeof(int) * NBMAX;
    int* rowptr   = (int*)p;           p += sizeof(int) * (N + 4);
    uint32* pairs = (uint32*)p;        p += sizeof(uint32) * ((size_t)E + 16 * NBMAX);
    int* srcs     = (int*)p;           p += sizeof(int) * E;
    ushort16* xl  = (ushort16*)p;      p += sizeof(ushort16) * (size_t)N * HID;
    float* xr     = (float*)p;         p += sizeof(float) * (size_t)N * HID;
    ushort16* hl  = (ushort16*)p;      p += sizeof(ushort16) * (size_t)N * OUT_DIM;
    float* hr     = (float*)p;         p += sizeof(float) * (size_t)N * OUT_DIM;

    hipMemsetAsync(bhist, 0, sizeof(int) * NBMAX, stream);

    bucket_hist_kernel<<<512, 256, 0, stream>>>(dst, bhist, E);
    bucket_scan_kernel<<<1, 512, 0, stream>>>(bhist, ebase, pbase, bcur, rowptr, NB, N, E);
    partition_kernel<<<(E + CHUNK - 1) / CHUNK, 256, 0, stream>>>(src, dst, bcur, pairs, E, NB);
    fine_bin_kernel<<<NB, 256, 0, stream>>>(pairs, bhist, ebase, pbase, rowptr, srcs, N);
    gemm1_mfma_kernel<<<(N + 63) / 64, 256, 0, stream>>>(x, Wl1, Wr1, b1, xl, xr, N);
    agg_mid_kernel<<<(N + 31) / 32, 256, 0, stream>>>(rowptr, srcs, (const uint4*)xl, xr,
                                                      Wl2, Wr2, b2, (uint4*)hl, hr, N);
    agg2_final_kernel<<<(N + 63) / 64, 256, 0, stream>>>(rowptr, srcs, (const uint4*)hl, hr,
                                                         (float*)d_out, N);
}